// Round 6
// baseline (281.736 us; speedup 1.0000x reference)
//
#include <hip/hip_runtime.h>

// VolumeRenderer: N=65536 rays, L=192 samples. fp32.
//   delta[l] = depth[l+1]-depth[l] (last = 1e10)
//   alpha = 1 - exp(-relu(sigma)*delta);  w = alpha*(1-alpha+1e-10)
//   color = sum_l sigmoid(rgb)*w -> (N,3);  depth_out = sum_l w*depth -> (N,1)
//
// History:
//  R1/R2/R5 wave-per-ray (scalar dword loads): all pinned at 93us, VGPR 12-16.
//    Compiler serializes scalar loads (no MLP); wave lifetime ~19k cyc of vmcnt.
//  R3 thread-per-half-ray (float4 loops): VGPR=40, 2.96 TB/s sustained --
//    proves float4 loads DO get clustered -- but loop-carried line reuse across
//    512 threads/CU thrashed L1 (FETCH 126->394 MB), 137us.
//  R6: 16 threads/ray x 12 samples, straight-line: 15 independent float4 loads
//    per thread (zero cross-iteration reuse -> no thrash), deltas thread-local
//    (+1 boundary dword), reduction = single 16-lane DPP row (4 adds/value).

constexpr int L   = 192;
constexpr int TPR = 16;   // threads per ray
constexpr int SPT = 12;   // samples per thread

__device__ __forceinline__ float fast_sigmoid(float x) {
    return __builtin_amdgcn_rcpf(1.0f + __expf(-x));
}

template <int CTRL>
__device__ __forceinline__ float dpp_add(float x) {
    int s = __builtin_amdgcn_update_dpp(0, __builtin_bit_cast(int, x),
                                        CTRL, 0xf, 0xf, true);
    return x + __builtin_bit_cast(float, s);
}

// sum over each 16-lane DPP row; lane 15 of the row holds the total
__device__ __forceinline__ float row_sum16(float x) {
    x = dpp_add<0x111>(x);  // row_shr:1
    x = dpp_add<0x112>(x);  // row_shr:2
    x = dpp_add<0x114>(x);  // row_shr:4
    x = dpp_add<0x118>(x);  // row_shr:8
    return x;
}

__global__ __launch_bounds__(256, 4) void volrender_kernel(
    const float* __restrict__ depth, const float* __restrict__ rgb,
    const float* __restrict__ sigma, float* __restrict__ out, int n_rays)
{
    const int t   = blockIdx.x * 256 + threadIdx.x;
    const int ray = t >> 4;          // 16-lane DPP row == one ray
    const int seg = t & 15;
    const size_t sbase = (size_t)ray * L + seg * SPT;

    const float4* dp4 = (const float4*)(depth + sbase);      // 48B-aligned
    const float4* sp4 = (const float4*)(sigma + sbase);
    const float4* cp4 = (const float4*)(rgb + sbase * 3);    // 144B-aligned

    // ---- 15 independent float4 loads + 1 boundary dword, all up-front ----
    float4 D0 = dp4[0], D1 = dp4[1], D2 = dp4[2];
    float4 S0 = sp4[0], S1 = sp4[1], S2 = sp4[2];
    float4 C0 = cp4[0], C1 = cp4[1], C2 = cp4[2], C3 = cp4[3], C4 = cp4[4],
           C5 = cp4[5], C6 = cp4[6], C7 = cp4[7], C8 = cp4[8];
    const size_t lastidx = (size_t)n_rays * L - 1;
    const size_t nidx = sbase + SPT;                 // next thread's 1st depth
    const float dnext = depth[nidx <= lastidx ? nidx : lastidx];

    // register arrays (fully unrolled constant indices -> stays in VGPRs)
    float d[13], s[12], c[36];
    ((float4*)d)[0] = D0; ((float4*)d)[1] = D1; ((float4*)d)[2] = D2;
    d[12] = dnext;
    ((float4*)s)[0] = S0; ((float4*)s)[1] = S1; ((float4*)s)[2] = S2;
    ((float4*)c)[0] = C0; ((float4*)c)[1] = C1; ((float4*)c)[2] = C2;
    ((float4*)c)[3] = C3; ((float4*)c)[4] = C4; ((float4*)c)[5] = C5;
    ((float4*)c)[6] = C6; ((float4*)c)[7] = C7; ((float4*)c)[8] = C8;

    float cr = 0.f, cg = 0.f, cb = 0.f, dd = 0.f;
    #pragma unroll
    for (int j = 0; j < SPT; ++j) {
        float delta = d[j + 1] - d[j];
        if (j == SPT - 1)                       // folded per unrolled iter
            delta = (seg == TPR - 1) ? 1e10f : delta;   // sample 191
        float a = 1.0f - __expf(-fmaxf(s[j], 0.0f) * delta);
        float w = a * (1.0f - a + 1e-10f);
        cr += fast_sigmoid(c[3 * j + 0]) * w;
        cg += fast_sigmoid(c[3 * j + 1]) * w;
        cb += fast_sigmoid(c[3 * j + 2]) * w;
        dd += w * d[j];
    }

    // ---- 16-lane reduction, one DPP row per ray ----
    cr = row_sum16(cr);
    cg = row_sum16(cg);
    cb = row_sum16(cb);
    dd = row_sum16(dd);

    if (seg == TPR - 1) {                        // lane 15 of the row
        out[ray * 3 + 0] = cr;
        out[ray * 3 + 1] = cg;
        out[ray * 3 + 2] = cb;
        out[(size_t)n_rays * 3 + ray] = dd;      // depth block follows colors
    }
}

extern "C" void kernel_launch(void* const* d_in, const int* in_sizes, int n_in,
                              void* d_out, int out_size, void* d_ws, size_t ws_size,
                              hipStream_t stream) {
    const float* depth = (const float*)d_in[0];
    const float* rgb   = (const float*)d_in[1];
    const float* sigma = (const float*)d_in[2];
    float* out = (float*)d_out;
    const int n_rays  = in_sizes[0] / L;                 // 65536
    const int threads = n_rays * TPR;                    // 1,048,576
    volrender_kernel<<<threads / 256, 256, 0, stream>>>(depth, rgb, sigma, out, n_rays);
}